// Round 1
// baseline (425.889 us; speedup 1.0000x reference)
//
#include <hip/hip_runtime.h>
#include <stdint.h>

typedef int v4i __attribute__((ext_vector_type(4)));

#define GLOBAL_AS __attribute__((address_space(1)))
#define LDS_AS __attribute__((address_space(3)))

// Exact replication of reference rounding:
// q = clamp(rint(x / s + z), 0, 255); store (q - zi) as int8.
__device__ __forceinline__ int quant1(float x, float s, float z, int zi) {
    float q = rintf(x / s + z);          // IEEE division + round-half-even, matches np
    q = fminf(fmaxf(q, 0.0f), 255.0f);
    return (int)q - zi;
}

__device__ __forceinline__ unsigned qpack4(float4 v, float s, float z, int zi) {
    unsigned q0 = (unsigned)(quant1(v.x, s, z, zi) & 255);
    unsigned q1 = (unsigned)(quant1(v.y, s, z, zi) & 255);
    unsigned q2 = (unsigned)(quant1(v.z, s, z, zi) & 255);
    unsigned q3 = (unsigned)(quant1(v.w, s, z, zi) & 255);
    return q0 | (q1 << 8) | (q2 << 16) | (q3 << 24);
}

// ---------------- quantize x1 (elementwise, keeps layout [*, K]) ----------------
__global__ __launch_bounds__(256) void quant_lin(const float* __restrict__ x,
                                                 int8_t* __restrict__ out,
                                                 const float* __restrict__ sp,
                                                 const float* __restrict__ zp,
                                                 long n16) {
    float s = sp[0], z = zp[0];
    int zi = (int)rintf(z);
    long i = (long)blockIdx.x * 256 + threadIdx.x;
    if (i >= n16) return;
    const float4* xv = (const float4*)x;
    uint4 w;
    w.x = qpack4(xv[i * 4 + 0], s, z, zi);
    w.y = qpack4(xv[i * 4 + 1], s, z, zi);
    w.z = qpack4(xv[i * 4 + 2], s, z, zi);
    w.w = qpack4(xv[i * 4 + 3], s, z, zi);
    ((uint4*)out)[i] = w;
}

// ------------- quantize x2 [K][N] -> int8 transposed [N][K] -------------
// 64x64 tile per block; 4x4 register micro-transpose; LDS [64][17] dwords to
// keep both global reads (along N) and global writes (along K) coalesced.
__global__ __launch_bounds__(256) void quant_bt(const float* __restrict__ x,
                                                int8_t* __restrict__ out,
                                                const float* __restrict__ sp,
                                                const float* __restrict__ zp) {
    constexpr int K = 4096, N = 4096;
    float s = sp[0], z = zp[0];
    int zi = (int)rintf(z);
    size_t bin = (size_t)blockIdx.z * K * N;
    int tid = threadIdx.x;
    int bk = tid >> 4;   // 0..15: k-block of 4 rows
    int bn = tid & 15;   // 0..15: n-block of 4 cols
    int k0 = blockIdx.y * 64, n0 = blockIdx.x * 64;
    __shared__ unsigned lds[64][17];
    unsigned o0 = 0, o1 = 0, o2 = 0, o3 = 0;
#pragma unroll
    for (int r = 0; r < 4; ++r) {
        float4 v = *(const float4*)(x + bin + (size_t)(k0 + bk * 4 + r) * N + n0 + bn * 4);
        o0 |= (unsigned)(quant1(v.x, s, z, zi) & 255) << (r * 8);
        o1 |= (unsigned)(quant1(v.y, s, z, zi) & 255) << (r * 8);
        o2 |= (unsigned)(quant1(v.z, s, z, zi) & 255) << (r * 8);
        o3 |= (unsigned)(quant1(v.w, s, z, zi) & 255) << (r * 8);
    }
    // lds[n_local][k_dword]: dword bk holds k-bytes bk*4..bk*4+3 of row n
    lds[bn * 4 + 0][bk] = o0;
    lds[bn * 4 + 1][bk] = o1;
    lds[bn * 4 + 2][bk] = o2;
    lds[bn * 4 + 3][bk] = o3;
    __syncthreads();
    int nl = tid >> 2, ch = tid & 3;
    uint4 w;
    w.x = lds[nl][ch * 4 + 0];
    w.y = lds[nl][ch * 4 + 1];
    w.z = lds[nl][ch * 4 + 2];
    w.w = lds[nl][ch * 4 + 3];
    *(uint4*)(out + bin + (size_t)(n0 + nl) * K + k0 + ch * 16) = w;
}

// ---------------- int8 GEMM: C[b] = Aq[b](MxK) * BqT[b](NxK)^T ----------------
// 128x128 tile, BK=64, 4 waves (2x2, each 64x64), mfma_i32_16x16x64_i8.
// LDS is fragment-major: flat idx = cb*128 + row, 16 bytes each, so the
// global_load_lds (lane-linear dest) sources are pre-swizzled per-lane and
// every ds_read_b128 fragment load is contiguous-per-16-lane (conflict-free).
__global__ __launch_bounds__(256) void gemm_i8(const int8_t* __restrict__ A,
                                               const int8_t* __restrict__ Bt,
                                               float* __restrict__ C,
                                               const float* __restrict__ sp1,
                                               const float* __restrict__ sp2) {
    constexpr int M = 2048, N = 4096, K = 4096;
    constexpr int BM = 128, BN = 128, BK = 64;
    constexpr int NBN = N / BN;  // 32

    int b = blockIdx.z;
    const int8_t* Ab = A + (size_t)b * M * K;
    const int8_t* Bb = Bt + (size_t)b * N * K;
    float* Cb = C + (size_t)b * M * N;

    // XCD-aware swizzle; grid.x = 512, divisible by 8 -> bijective
    int nwg = gridDim.x;
    int wg = blockIdx.x;
    wg = (wg & 7) * (nwg >> 3) + (wg >> 3);
    int by = wg / NBN, bx = wg % NBN;
    int m0 = by * BM, n0 = bx * BN;

    int tid = threadIdx.x;
    int lane = tid & 63, wid = tid >> 6;
    int wr = wid >> 1, wc = wid & 1;
    int l15 = lane & 15, cb = lane >> 4;

    __shared__ v4i lds4[2][2][512];  // [buf][A/B][cb*128+row] -> 16 bytes

    v4i zero = {0, 0, 0, 0};
    v4i acc[4][4];
#pragma unroll
    for (int m = 0; m < 4; ++m)
#pragma unroll
        for (int n = 0; n < 4; ++n) acc[m][n] = zero;

#define STAGE(buf, kt)                                                                     \
    {                                                                                      \
        int k0s = (kt)*BK;                                                                 \
        _Pragma("unroll") for (int j = 0; j < 2; ++j) {                                    \
            int idx = j * 256 + tid;                                                       \
            int rowi = idx & 127;                                                          \
            int cbi = idx >> 7;                                                            \
            __builtin_amdgcn_global_load_lds(                                              \
                (const GLOBAL_AS void*)(Ab + (size_t)(m0 + rowi) * K + k0s + cbi * 16),    \
                (LDS_AS void*)&lds4[buf][0][idx], 16, 0, 0);                               \
            __builtin_amdgcn_global_load_lds(                                              \
                (const GLOBAL_AS void*)(Bb + (size_t)(n0 + rowi) * K + k0s + cbi * 16),    \
                (LDS_AS void*)&lds4[buf][1][idx], 16, 0, 0);                               \
        }                                                                                  \
    }

#define COMPUTE(buf)                                                                       \
    {                                                                                      \
        const v4i* As4 = &lds4[buf][0][0];                                                 \
        const v4i* Bs4 = &lds4[buf][1][0];                                                 \
        v4i af[4], bf[4];                                                                  \
        _Pragma("unroll") for (int m = 0; m < 4; ++m)                                      \
            af[m] = As4[cb * 128 + wr * 64 + m * 16 + l15];                                \
        _Pragma("unroll") for (int n = 0; n < 4; ++n)                                      \
            bf[n] = Bs4[cb * 128 + wc * 64 + n * 16 + l15];                                \
        _Pragma("unroll") for (int m = 0; m < 4; ++m)                                      \
            _Pragma("unroll") for (int n = 0; n < 4; ++n)                                  \
                acc[m][n] = __builtin_amdgcn_mfma_i32_16x16x64_i8(af[m], bf[n],            \
                                                                  acc[m][n], 0, 0, 0);     \
    }

    STAGE(0, 0);
    __syncthreads();
    int cur = 0;
    for (int kt = 0; kt < K / BK - 1; ++kt) {
        STAGE(cur ^ 1, kt + 1);
        COMPUTE(cur);
        __syncthreads();
        cur ^= 1;
    }
    COMPUTE(cur);

    float sc = sp1[0] * sp2[0];
    int r0 = (lane >> 4) * 4;
    int c0 = l15;
#pragma unroll
    for (int m = 0; m < 4; ++m) {
#pragma unroll
        for (int n = 0; n < 4; ++n) {
            float* p = Cb + (size_t)(m0 + wr * 64 + m * 16 + r0) * N + (n0 + wc * 64 + n * 16 + c0);
#pragma unroll
            for (int r = 0; r < 4; ++r) p[(size_t)r * N] = sc * (float)acc[m][n][r];
        }
    }
#undef STAGE
#undef COMPUTE
}

extern "C" void kernel_launch(void* const* d_in, const int* in_sizes, int n_in,
                              void* d_out, int out_size, void* d_ws, size_t ws_size,
                              hipStream_t stream) {
    const float* x1 = (const float*)d_in[0];
    const float* x2 = (const float*)d_in[1];
    const float* s1 = (const float*)d_in[2];
    const float* z1 = (const float*)d_in[3];
    const float* s2 = (const float*)d_in[4];
    const float* z2 = (const float*)d_in[5];
    float* out = (float*)d_out;

    const int B = 4, M = 2048, K = 4096, N = 4096;
    const size_t ASZ = (size_t)B * M * K;   // int8 bytes for all of x1
    const size_t BSZ = (size_t)B * K * N;   // int8 bytes for all of x2
    dim3 blk(256);

    if (ws_size >= ASZ + BSZ) {
        // Fused path: quantize everything, one batched GEMM launch.
        int8_t* Aq = (int8_t*)d_ws;
        int8_t* Bq = Aq + ASZ;
        long n16 = (long)(ASZ / 16);
        quant_lin<<<dim3((unsigned)(n16 / 256)), blk, 0, stream>>>(x1, Aq, s1, z1, n16);
        quant_bt<<<dim3(N / 64, K / 64, B), blk, 0, stream>>>(x2, Bq, s2, z2);
        gemm_i8<<<dim3((M / 128) * (N / 128), 1, B), blk, 0, stream>>>(Aq, Bq, out, s1, s2);
    } else {
        // Per-batch path: needs only M*K + K*N = 25.2 MB of workspace.
        const size_t AB = (size_t)M * K, BB = (size_t)K * N;
        int8_t* Aq = (int8_t*)d_ws;
        int8_t* Bq = Aq + AB;
        for (int b = 0; b < B; ++b) {
            long n16 = (long)(AB / 16);
            quant_lin<<<dim3((unsigned)(n16 / 256)), blk, 0, stream>>>(x1 + (size_t)b * AB, Aq, s1, z1, n16);
            quant_bt<<<dim3(N / 64, K / 64, 1), blk, 0, stream>>>(x2 + (size_t)b * BB, Bq, s2, z2);
            gemm_i8<<<dim3((M / 128) * (N / 128), 1, 1), blk, 0, stream>>>(Aq, Bq, out + (size_t)b * M * N, s1, s2);
        }
    }
}

// Round 2
// 260.451 us; speedup vs baseline: 1.6352x; 1.6352x over previous
//
#include <hip/hip_runtime.h>
#include <stdint.h>

typedef int v4i __attribute__((ext_vector_type(4)));

#define GLOBAL_AS __attribute__((address_space(1)))
#define LDS_AS __attribute__((address_space(3)))

// Exact replication of reference rounding:
// q = clamp(rint(x / s + z), 0, 255); store (q - zi) as int8.
__device__ __forceinline__ int quant1(float x, float s, float z, int zi) {
    float q = rintf(x / s + z);          // IEEE division + round-half-even, matches np
    q = fminf(fmaxf(q, 0.0f), 255.0f);
    return (int)q - zi;
}

__device__ __forceinline__ unsigned qpack4(float4 v, float s, float z, int zi) {
    unsigned q0 = (unsigned)(quant1(v.x, s, z, zi) & 255);
    unsigned q1 = (unsigned)(quant1(v.y, s, z, zi) & 255);
    unsigned q2 = (unsigned)(quant1(v.z, s, z, zi) & 255);
    unsigned q3 = (unsigned)(quant1(v.w, s, z, zi) & 255);
    return q0 | (q1 << 8) | (q2 << 16) | (q3 << 24);
}

// ---------------- quantize x1 (elementwise, keeps layout [*, K]) ----------------
__global__ __launch_bounds__(256) void quant_lin(const float* __restrict__ x,
                                                 int8_t* __restrict__ out,
                                                 const float* __restrict__ sp,
                                                 const float* __restrict__ zp,
                                                 long n16) {
    float s = sp[0], z = zp[0];
    int zi = (int)rintf(z);
    long i = (long)blockIdx.x * 256 + threadIdx.x;
    if (i >= n16) return;
    const float4* xv = (const float4*)x;
    uint4 w;
    w.x = qpack4(xv[i * 4 + 0], s, z, zi);
    w.y = qpack4(xv[i * 4 + 1], s, z, zi);
    w.z = qpack4(xv[i * 4 + 2], s, z, zi);
    w.w = qpack4(xv[i * 4 + 3], s, z, zi);
    ((uint4*)out)[i] = w;
}

// ------------- quantize x2 [K][N] -> int8 transposed [N][K] -------------
__global__ __launch_bounds__(256) void quant_bt(const float* __restrict__ x,
                                                int8_t* __restrict__ out,
                                                const float* __restrict__ sp,
                                                const float* __restrict__ zp) {
    constexpr int K = 4096, N = 4096;
    float s = sp[0], z = zp[0];
    int zi = (int)rintf(z);
    size_t bin = (size_t)blockIdx.z * K * N;
    int tid = threadIdx.x;
    int bk = tid >> 4;   // 0..15: k-block of 4 rows
    int bn = tid & 15;   // 0..15: n-block of 4 cols
    int k0 = blockIdx.y * 64, n0 = blockIdx.x * 64;
    __shared__ unsigned lds[64][17];
    unsigned o0 = 0, o1 = 0, o2 = 0, o3 = 0;
#pragma unroll
    for (int r = 0; r < 4; ++r) {
        float4 v = *(const float4*)(x + bin + (size_t)(k0 + bk * 4 + r) * N + n0 + bn * 4);
        o0 |= (unsigned)(quant1(v.x, s, z, zi) & 255) << (r * 8);
        o1 |= (unsigned)(quant1(v.y, s, z, zi) & 255) << (r * 8);
        o2 |= (unsigned)(quant1(v.z, s, z, zi) & 255) << (r * 8);
        o3 |= (unsigned)(quant1(v.w, s, z, zi) & 255) << (r * 8);
    }
    lds[bn * 4 + 0][bk] = o0;
    lds[bn * 4 + 1][bk] = o1;
    lds[bn * 4 + 2][bk] = o2;
    lds[bn * 4 + 3][bk] = o3;
    __syncthreads();
    int nl = tid >> 2, ch = tid & 3;
    uint4 w;
    w.x = lds[nl][ch * 4 + 0];
    w.y = lds[nl][ch * 4 + 1];
    w.z = lds[nl][ch * 4 + 2];
    w.w = lds[nl][ch * 4 + 3];
    *(uint4*)(out + bin + (size_t)(n0 + nl) * K + k0 + ch * 16) = w;
}

// ---------------- int8 GEMM, 256x256 tile, 8-phase schedule ----------------
// C[b] = Aq[b](MxK) * BqT[b](NxK)^T, mfma_i32_16x16x64_i8.
// 512 threads = 8 waves (2Mx4N), per-wave 128x64 output, BK=128.
// LDS 128 KiB: [buf][mat][khalf] regions of 256 rows x 64 B, chunk-XOR
// swizzled via pre-swizzled global source (linear LDS dest for gload_lds).
// Counted vmcnt(4) at phases 2 & 4; K-half regions are written exactly one
// tile after their last reader (dead-region schedule).
__global__ __launch_bounds__(512, 2) void gemm_i8(const int8_t* __restrict__ A,
                                                  const int8_t* __restrict__ Bt,
                                                  float* __restrict__ C,
                                                  const float* __restrict__ sp1,
                                                  const float* __restrict__ sp2) {
    constexpr int M = 2048, N = 4096, K = 4096;
    constexpr int BM = 256, BN = 256, BK = 128;
    constexpr int NT = K / BK;   // 32
    constexpr int NBN = N / BN;  // 16

    extern __shared__ char smem[];

    int b = blockIdx.z;
    const int8_t* Ab = A + (size_t)b * M * K;
    const int8_t* Bb = Bt + (size_t)b * N * K;
    float* Cb = C + (size_t)b * M * N;

    // XCD-aware swizzle; grid.x = 128, divisible by 8 -> bijective
    int nwg = gridDim.x;
    int wg = blockIdx.x;
    wg = (wg & 7) * (nwg >> 3) + (wg >> 3);
    int by = wg / NBN, bx = wg % NBN;
    int m0 = by * BM, n0 = bx * BN;

    int tid = threadIdx.x;
    int lane = tid & 63, wid = tid >> 6;
    int wr = wid >> 2, wc = wid & 3;  // 2 x 4 waves
    int l15 = lane & 15, cb = lane >> 4;

    const int8_t* Abase = Ab + (size_t)m0 * K;
    const int8_t* Bbase = Bb + (size_t)n0 * K;

    // per-lane swizzled within-region byte offsets for fragment ds_reads
    int aoff[8], boff[4];
#pragma unroll
    for (int m = 0; m < 8; ++m) {
        int r = wr * 128 + m * 16 + l15;
        aoff[m] = r * 64 + ((cb ^ ((r >> 1) & 3)) * 16);
    }
#pragma unroll
    for (int n = 0; n < 4; ++n) {
        int r = wc * 64 + n * 16 + l15;
        boff[n] = r * 64 + ((cb ^ ((r >> 1) & 3)) * 16);
    }

    v4i zero = {0, 0, 0, 0};
    v4i acc[8][4];
#pragma unroll
    for (int m = 0; m < 8; ++m)
#pragma unroll
        for (int n = 0; n < 4; ++n) acc[m][n] = zero;

// stage one K-half of one matrix for tile jt1 (2 x global_load_lds, 16 KB)
#define ISSUE(mat, base, jt1, kh)                                                      \
    {                                                                                  \
        const int8_t* gb = (base) + (size_t)(jt1) * BK + (size_t)(kh) * 64;            \
        char* dst = smem + ((((jt1) & 1) * 2 + (mat)) * 2 + (kh)) * 16384;             \
        _Pragma("unroll") for (int j = 0; j < 2; ++j) {                                \
            int idx = j * 512 + tid;                                                   \
            int row = idx >> 2;                                                        \
            int cc = idx & 3;                                                          \
            int sc_ = cc ^ ((row >> 1) & 3);                                           \
            __builtin_amdgcn_global_load_lds(                                          \
                (const GLOBAL_AS void*)(gb + (size_t)row * K + sc_ * 16),              \
                (LDS_AS void*)(dst + idx * 16), 16, 0, 0);                             \
        }                                                                              \
    }

#define PHASE(buf, kk, mh, DOISSUE, DOWAIT)                                            \
    {                                                                                  \
        const char* Ar = smem + ((buf) * 4 + 0 + (kk)) * 16384;                        \
        const char* Br = smem + ((buf) * 4 + 2 + (kk)) * 16384;                        \
        v4i af[4], bf[4];                                                              \
        _Pragma("unroll") for (int m = 0; m < 4; ++m)                                  \
            af[m] = *(const v4i*)(Ar + aoff[(mh) * 4 + m]);                            \
        _Pragma("unroll") for (int n = 0; n < 4; ++n)                                  \
            bf[n] = *(const v4i*)(Br + boff[n]);                                       \
        DOISSUE;                                                                       \
        __builtin_amdgcn_s_barrier();                                                  \
        asm volatile("s_waitcnt lgkmcnt(0)" ::: "memory");                             \
        __builtin_amdgcn_sched_barrier(0);                                             \
        __builtin_amdgcn_s_setprio(1);                                                 \
        _Pragma("unroll") for (int m = 0; m < 4; ++m)                                  \
            _Pragma("unroll") for (int n = 0; n < 4; ++n)                              \
                acc[(mh) * 4 + m][n] = __builtin_amdgcn_mfma_i32_16x16x64_i8(          \
                    af[m], bf[n], acc[(mh) * 4 + m][n], 0, 0, 0);                      \
        __builtin_amdgcn_s_setprio(0);                                                 \
        DOWAIT;                                                                        \
        __builtin_amdgcn_s_barrier();                                                  \
    }

    // prologue: stage tile 0 fully; retire its K-half 0 before entering loop
    ISSUE(0, Abase, 0, 0);
    ISSUE(1, Bbase, 0, 0);
    ISSUE(0, Abase, 0, 1);
    ISSUE(1, Bbase, 0, 1);
    asm volatile("s_waitcnt vmcnt(4)" ::: "memory");
    __builtin_amdgcn_s_barrier();

    for (int jt = 0; jt < NT; ++jt) {
        int buf = jt & 1;
        if (jt + 1 < NT) {
            PHASE(buf, 0, 0, ISSUE(0, Abase, jt + 1, 0), )
            PHASE(buf, 0, 1, ISSUE(1, Bbase, jt + 1, 0),
                  asm volatile("s_waitcnt vmcnt(4)" ::: "memory"))
            PHASE(buf, 1, 0, ISSUE(0, Abase, jt + 1, 1), )
            PHASE(buf, 1, 1, ISSUE(1, Bbase, jt + 1, 1),
                  asm volatile("s_waitcnt vmcnt(4)" ::: "memory"))
        } else {
            PHASE(buf, 0, 0, , )
            PHASE(buf, 0, 1, , asm volatile("s_waitcnt vmcnt(0)" ::: "memory"))
            PHASE(buf, 1, 0, , )
            PHASE(buf, 1, 1, , )
        }
    }

    float sc = sp1[0] * sp2[0];
    int r0 = cb * 4;
#pragma unroll
    for (int m = 0; m < 8; ++m) {
#pragma unroll
        for (int n = 0; n < 4; ++n) {
            float* p = Cb + (size_t)(m0 + wr * 128 + m * 16 + r0) * N +
                       (n0 + wc * 64 + n * 16 + l15);
#pragma unroll
            for (int r = 0; r < 4; ++r) p[(size_t)r * N] = sc * (float)acc[m][n][r];
        }
    }
#undef ISSUE
#undef PHASE
}

extern "C" void kernel_launch(void* const* d_in, const int* in_sizes, int n_in,
                              void* d_out, int out_size, void* d_ws, size_t ws_size,
                              hipStream_t stream) {
    const float* x1 = (const float*)d_in[0];
    const float* x2 = (const float*)d_in[1];
    const float* s1 = (const float*)d_in[2];
    const float* z1 = (const float*)d_in[3];
    const float* s2 = (const float*)d_in[4];
    const float* z2 = (const float*)d_in[5];
    float* out = (float*)d_out;

    const int B = 4, M = 2048, K = 4096, N = 4096;
    const size_t ASZ = (size_t)B * M * K;   // int8 bytes for all of x1
    const size_t BSZ = (size_t)B * K * N;   // int8 bytes for all of x2
    dim3 blk(256);

    static int lds_attr_set = 0;
    if (!lds_attr_set) {
        (void)hipFuncSetAttribute((const void*)gemm_i8,
                                  hipFuncAttributeMaxDynamicSharedMemorySize, 131072);
        lds_attr_set = 1;
    }

    if (ws_size >= ASZ + BSZ) {
        int8_t* Aq = (int8_t*)d_ws;
        int8_t* Bq = Aq + ASZ;
        long n16 = (long)(ASZ / 16);
        quant_lin<<<dim3((unsigned)(n16 / 256)), blk, 0, stream>>>(x1, Aq, s1, z1, n16);
        quant_bt<<<dim3(N / 64, K / 64, B), blk, 0, stream>>>(x2, Bq, s2, z2);
        gemm_i8<<<dim3((M / 256) * (N / 256), 1, B), dim3(512), 131072, stream>>>(
            Aq, Bq, out, s1, s2);
    } else {
        const size_t AB = (size_t)M * K, BB = (size_t)K * N;
        int8_t* Aq = (int8_t*)d_ws;
        int8_t* Bq = Aq + AB;
        for (int b = 0; b < B; ++b) {
            long n16 = (long)(AB / 16);
            quant_lin<<<dim3((unsigned)(n16 / 256)), blk, 0, stream>>>(x1 + (size_t)b * AB, Aq, s1, z1, n16);
            quant_bt<<<dim3(N / 64, K / 64, 1), blk, 0, stream>>>(x2 + (size_t)b * BB, Bq, s2, z2);
            gemm_i8<<<dim3((M / 256) * (N / 256), 1, 1), dim3(512), 131072, stream>>>(
                Aq, Bq, out + (size_t)b * M * N, s1, s2);
        }
    }
}